// Round 1
// baseline (463.861 us; speedup 1.0000x reference)
//
#include <hip/hip_runtime.h>
#include <stdint.h>

// Problem constants (fixed by setup_inputs): B=4, C=128, H=W=128, N=9, OC=256, stride=1
#define CIN   128
#define HDIM  128
#define WDIM  128
#define HWSZ  16384      // 128*128
#define NP    9
#define OCH   256
#define KDIM  1152       // NP*CIN

typedef __bf16 bf16_t;
typedef __bf16 bf16x8 __attribute__((ext_vector_type(8)));
typedef float  f32x4  __attribute__((ext_vector_type(4)));

// ---------------------------------------------------------------------------
// K2: build B_T[o][k] bf16, k = n*128 + c   (= w_conv[o][c][n])
// grid (9, 256) x 128 threads
// ---------------------------------------------------------------------------
__global__ void k_bt(const float* __restrict__ wc, bf16_t* __restrict__ bt) {
  int c = threadIdx.x;      // 0..127
  int n = blockIdx.x;       // 0..8
  int o = blockIdx.y;       // 0..255
  bt[o * KDIM + n * 128 + c] = (bf16_t)wc[(o * CIN + c) * NP + n];
}

// ---------------------------------------------------------------------------
// K1: offset conv (3x3, pad 1, 128->18) + bilinear meta
// one block per (b,i); 256 threads = 128 j x 2 c-halves
// meta layout: [b][i][n][j]  (coalesced along j)
// ---------------------------------------------------------------------------
__global__ __launch_bounds__(256) void k_conv_meta(
    const float* __restrict__ x, const float* __restrict__ wp,
    const float* __restrict__ bp, int* __restrict__ midx,
    float4* __restrict__ mw)
{
  int blk = blockIdx.x;
  int bb = blk >> 7, ii = blk & 127;
  int tid = threadIdx.x;
  int j = tid & 127;
  int chalf = tid >> 7;

  float acc[18];
#pragma unroll
  for (int o = 0; o < 18; ++o) acc[o] = 0.f;

  const float* xb = x + (size_t)bb * CIN * HWSZ;
  for (int c = chalf * 64; c < chalf * 64 + 64; ++c) {
    const float* xc = xb + c * HWSZ;
    float xv[9];
#pragma unroll
    for (int dy = 0; dy < 3; ++dy) {
      int r = ii + dy - 1;
      bool rok = ((unsigned)r < 128u);
#pragma unroll
      for (int dx = 0; dx < 3; ++dx) {
        int cc = j + dx - 1;
        bool ok = rok && ((unsigned)cc < 128u);
        xv[dy * 3 + dx] = ok ? xc[r * 128 + cc] : 0.f;
      }
    }
    const float* wr = wp + c * 9;   // wp[o][c][tap] = wp[o*1152 + c*9 + tap]
#pragma unroll
    for (int o = 0; o < 18; ++o) {
#pragma unroll
      for (int t = 0; t < 9; ++t)
        acc[o] += xv[t] * wr[o * 1152 + t];   // uniform index -> s_load
    }
  }

  __shared__ float red[128][18];
  if (chalf == 1) {
#pragma unroll
    for (int o = 0; o < 18; ++o) red[j][o] = acc[o];
  }
  __syncthreads();
  if (chalf == 0) {
#pragma unroll
    for (int o = 0; o < 18; ++o) acc[o] += red[j][o];

#pragma unroll
    for (int n = 0; n < NP; ++n) {
      float offx = acc[n] + bp[n];
      float offy = acc[9 + n] + bp[9 + n];
      float px = (float)ii + (float)(n / 3) + offx;   // row coord (H)
      float py = (float)j  + (float)(n % 3) + offy;   // col coord (W)
      float f0 = floorf(px), f1 = f0 + 1.f;
      float h0 = floorf(py), h1 = h0 + 1.f;
      int r0 = (int)fminf(fmaxf(f0, 0.f), 127.f);
      int r1 = (int)fminf(fmaxf(f1, 0.f), 127.f);
      int c0 = (int)fminf(fmaxf(h0, 0.f), 127.f);
      int c1 = (int)fminf(fmaxf(h1, 0.f), 127.f);
      float pxc = fminf(fmaxf(px, 0.f), 127.f);
      float pyc = fminf(fmaxf(py, 0.f), 127.f);
      float glt = (1.f + ((float)r0 - pxc)) * (1.f + ((float)c0 - pyc));
      float grb = (1.f - ((float)r1 - pxc)) * (1.f - ((float)c1 - pyc));
      float glb = (1.f + ((float)r0 - pxc)) * (1.f - ((float)c1 - pyc));
      float grt = (1.f - ((float)r1 - pxc)) * (1.f + ((float)c0 - pyc));
      int base = ((bb * 128 + ii) * NP + n) * 128 + j;
      midx[base] = r0 | (r1 << 8) | (c0 << 16) | (c1 << 24);
      mw[base] = make_float4(glt, grb, glb, grt);
    }
  }
}

// ---------------------------------------------------------------------------
// K3: fused gather + GEMM.  One block per (b,i): Mtile=128 (all j), Ntile=256.
// 512 threads = 8 waves; wave (mh = w&1, oq = w>>1) owns 64m x 64o C-tile.
// K-loop: BK=32 (chunk = one n, 32 channels). A gathered into LDS (bf16),
// B staged from L2-resident B_T. mfma_f32_16x16x32_bf16.
// ---------------------------------------------------------------------------
__global__ __launch_bounds__(512, 4) void k_gemm(
    const float* __restrict__ x, const bf16_t* __restrict__ bt,
    const int* __restrict__ midx, const float4* __restrict__ mw,
    float* __restrict__ out)
{
  // LDS: A 128x40 bf16 (80B rows, padded) | B 256x32 bf16 (64B rows) | meta
  __shared__ __align__(16) char smem[49664];
  bf16_t* Ald = (bf16_t*)smem;                 // 10240 B
  bf16_t* Bld = (bf16_t*)(smem + 10240);       // 16384 B
  int*    mi  = (int*)   (smem + 26624);       // 4608 B
  float4* mwl = (float4*)(smem + 31232);       // 18432 B

  int blk = blockIdx.x;
  int bb = blk >> 7, ii = blk & 127;
  int tid = threadIdx.x;
  int wave = tid >> 6, lane = tid & 63;
  int l15 = lane & 15, quad = lane >> 4;
  int mh = wave & 1;        // m half (64 rows)
  int oq = wave >> 1;       // o quarter (64 cols)
  int jloc = mh * 64 + lane;   // this thread's gather row (j), lanes consecutive
  int cgrp = oq;               // 0..3: which 8-channel group this wave gathers

  // load meta for this (b,i) into LDS
  {
    int base = (bb * 128 + ii) * (NP * 128);
    for (int t = tid; t < NP * 128; t += 512) mi[t] = midx[base + t];
    for (int t = tid; t < NP * 128; t += 512) mwl[t] = mw[base + t];
  }
  __syncthreads();

  const float* xb = x + (size_t)bb * CIN * HWSZ;

  f32x4 acc[4][4];
#pragma unroll
  for (int mt = 0; mt < 4; ++mt)
#pragma unroll
    for (int ot = 0; ot < 4; ++ot) acc[mt][ot] = (f32x4){0.f, 0.f, 0.f, 0.f};

#pragma unroll 1
  for (int kk = 0; kk < 36; ++kk) {
    int n = kk >> 2;
    int c0 = (kk & 3) * 32;

    // per-thread meta (j fixed, n fixed per chunk)
    int idx = mi[n * 128 + jloc];
    float4 g = mwl[n * 128 + jloc];
    int r0 = idx & 255, r1 = (idx >> 8) & 255;
    int q0 = (idx >> 16) & 255, q1 = (idx >> 24) & 255;
    int o00 = r0 * 128 + q0, o01 = r0 * 128 + q1;
    int o10 = r1 * 128 + q0, o11 = r1 * 128 + q1;

    __syncthreads();   // previous chunk's frag reads complete

    // ---- A gather: 8 channels per thread -> one ds_write_b128
    bf16x8 av;
#pragma unroll
    for (int it = 0; it < 8; ++it) {
      const float* p = xb + (c0 + cgrp * 8 + it) * HWSZ;  // scalar base
      float v = g.x * p[o00] + g.y * p[o11] + g.z * p[o01] + g.w * p[o10];
      av[it] = (bf16_t)v;
    }
    *(bf16x8*)(Ald + jloc * 40 + cgrp * 8) = av;

    // ---- B stage: 256 rows x 64B for this k-chunk (16KB), 2x16B per thread
    {
      const char* bsrc = (const char*)bt;
#pragma unroll
      for (int s = 0; s < 2; ++s) {
        int id = tid + s * 512;            // 0..1023
        int o = id >> 2, gg = id & 3;
        uint4 v = *(const uint4*)(bsrc + (size_t)o * (KDIM * 2) + kk * 64 + gg * 16);
        *(uint4*)((char*)Bld + o * 64 + gg * 16) = v;
      }
    }
    __syncthreads();

    // ---- fragments + MFMA
    bf16x8 af[4], bfr[4];
#pragma unroll
    for (int mt = 0; mt < 4; ++mt)
      af[mt] = *(bf16x8*)(Ald + (mh * 64 + mt * 16 + l15) * 40 + quad * 8);
#pragma unroll
    for (int ot = 0; ot < 4; ++ot) {
      int o = oq * 64 + ot * 16 + l15;
      bfr[ot] = *(bf16x8*)(Bld + o * 32 + quad * 8);
    }
#pragma unroll
    for (int mt = 0; mt < 4; ++mt)
#pragma unroll
      for (int ot = 0; ot < 4; ++ot)
        acc[mt][ot] = __builtin_amdgcn_mfma_f32_16x16x32_bf16(
            af[mt], bfr[ot], acc[mt][ot], 0, 0, 0);
  }

  // ---- epilogue: transpose 32-o x 128-j pieces through LDS, coalesced stores
  float* piece = (float*)smem;   // 32 rows x 132 floats (reuses A+B region)
  for (int p = 0; p < 8; ++p) {
    __syncthreads();
    if (oq == (p >> 1)) {
      int otbase = (p & 1) * 2;
#pragma unroll
      for (int t2 = 0; t2 < 2; ++t2) {
        int ot = otbase + t2;
        int o_ip = t2 * 16 + l15;                  // 0..31 within piece
#pragma unroll
        for (int mt = 0; mt < 4; ++mt) {
          int jj = mh * 64 + mt * 16 + quad * 4;   // C/D: row m = quad*4+reg
          *(f32x4*)(piece + o_ip * 132 + jj) = acc[mt][ot];
        }
      }
    }
    __syncthreads();
#pragma unroll
    for (int s = 0; s < 2; ++s) {
      int id = tid + s * 512;                      // 0..1023
      int o_ip = id >> 5, part = id & 31;
      f32x4 v = *(f32x4*)(piece + o_ip * 132 + part * 4);
      *(f32x4*)(out + (((size_t)bb * OCH + p * 32 + o_ip) * 128 + ii) * 128 + part * 4) = v;
    }
  }
}

// ---------------------------------------------------------------------------
extern "C" void kernel_launch(void* const* d_in, const int* in_sizes, int n_in,
                              void* d_out, int out_size, void* d_ws, size_t ws_size,
                              hipStream_t stream) {
  const float* x  = (const float*)d_in[0];   // (4,128,128,128)
  const float* wp = (const float*)d_in[1];   // (18,128,3,3)
  const float* bp = (const float*)d_in[2];   // (18,)
  const float* wc = (const float*)d_in[3];   // (256,128,9,1)
  float* out = (float*)d_out;                // (4,256,128,128)

  // workspace layout (needs ~13.5 MB)
  bf16_t* BT   = (bf16_t*)d_ws;                            // 589,824 B
  int*    MIDX = (int*)   ((char*)d_ws + (1u << 20));      // 2,359,296 B
  float4* MW   = (float4*)((char*)d_ws + (4u << 20));      // 9,437,184 B

  k_bt<<<dim3(9, 256), 128, 0, stream>>>(wc, BT);
  k_conv_meta<<<512, 256, 0, stream>>>(x, wp, bp, MIDX, MW);
  k_gemm<<<512, 512, 0, stream>>>(x, BT, MIDX, MW, out);
}

// Round 3
// 339.996 us; speedup vs baseline: 1.3643x; 1.3643x over previous
//
#include <hip/hip_runtime.h>
#include <stdint.h>

// Problem constants: B=4, C=128, H=W=128, N=9, OC=256, stride=1
#define CIN   128
#define HDIM  128
#define WDIM  128
#define HWSZ  16384
#define NP    9
#define OCH   256
#define KDIM  1152

typedef __bf16 bf16_t;
typedef __bf16 bf16x8 __attribute__((ext_vector_type(8)));
typedef float  f32x4  __attribute__((ext_vector_type(4)));
struct __attribute__((packed, aligned(4))) F2 { float x, y; };

// XCD-locality swizzle (grid=512): give XCD k a contiguous band of 64
// logical (b,ii) blocks so its 4MB L2 holds the x rows it needs.
__device__ __forceinline__ int swz(int hw) { return (hw & 7) * 64 + (hw >> 3); }

// ---------------------------------------------------------------------------
// B_T[o][k] bf16, k = n*128 + c  (= w_conv[o][c][n])
// ---------------------------------------------------------------------------
__global__ void k_bt(const float* __restrict__ wc, bf16_t* __restrict__ bt) {
  int c = threadIdx.x, n = blockIdx.x, o = blockIdx.y;
  bt[o * KDIM + n * 128 + c] = (bf16_t)wc[(o * CIN + c) * NP + n];
}

// ---------------------------------------------------------------------------
// Offset conv (3x3 pad 1, 128->18) in PURE FP32 + bilinear meta.
// fp32 is REQUIRED: bilinear sampling is discontinuous at borders (clamped
// corner weights sum to 2), so ~1e-3 offset error (bf16) flips samples.
// One block per (b,ii); 256 threads = 128 j x 2 c-halves.
// Weights scalarized via readfirstlane -> s_load (round-1 had 10.4k VMEM
// loads/thread here; this was the 230us).
// ---------------------------------------------------------------------------
__global__ __launch_bounds__(256) void k_conv_meta(
    const float* __restrict__ x, const float* __restrict__ wp,
    const float* __restrict__ bp, int* __restrict__ midx,
    float4* __restrict__ mw)
{
  int blk = swz(blockIdx.x);
  int bb = blk >> 7, ii = blk & 127;
  int tid = threadIdx.x;
  int j = tid & 127;
  int chalf = tid >> 7;     // wave-uniform (waves 0,1 -> 0; waves 2,3 -> 1)

  float acc[18];
#pragma unroll
  for (int o = 0; o < 18; ++o) acc[o] = 0.f;

  for (int c = chalf * 64; c < chalf * 64 + 64; ++c) {
    int cu = __builtin_amdgcn_readfirstlane(c);   // provably uniform
    const float* xc = x + ((size_t)bb * CIN + cu) * HWSZ;  // sgpr base
    float xv[9];
#pragma unroll
    for (int dy = 0; dy < 3; ++dy) {
      int r = ii + dy - 1;
      bool rok = ((unsigned)r < 128u);
#pragma unroll
      for (int dx = 0; dx < 3; ++dx) {
        int cc = j + dx - 1;
        bool ok = rok && ((unsigned)cc < 128u);
        xv[dy * 3 + dx] = ok ? xc[r * 128 + cc] : 0.f;   // j-coalesced
      }
    }
    const float* wr = wp + cu * 9;   // wp[o][c][tap]; uniform -> s_load
#pragma unroll
    for (int o = 0; o < 18; ++o) {
#pragma unroll
      for (int t = 0; t < 9; ++t)
        acc[o] += xv[t] * wr[o * 1152 + t];
    }
  }

  __shared__ float red[128][18];
  if (chalf == 1) {
#pragma unroll
    for (int o = 0; o < 18; ++o) red[j][o] = acc[o];
  }
  __syncthreads();
  if (chalf == 0) {
#pragma unroll
    for (int o = 0; o < 18; ++o) acc[o] += red[j][o];

#pragma unroll
    for (int n = 0; n < NP; ++n) {
      float offx = acc[n] + bp[n];
      float offy = acc[9 + n] + bp[9 + n];
      float px = (float)ii + (float)(n / 3) + offx;   // row coord (H)
      float py = (float)j  + (float)(n % 3) + offy;   // col coord (W)
      float f0 = floorf(px), f1 = f0 + 1.f;
      float h0 = floorf(py), h1 = h0 + 1.f;
      int r0 = (int)fminf(fmaxf(f0, 0.f), 127.f);
      int r1 = (int)fminf(fmaxf(f1, 0.f), 127.f);
      int c0 = (int)fminf(fmaxf(h0, 0.f), 127.f);
      int c1 = (int)fminf(fmaxf(h1, 0.f), 127.f);
      float pxc = fminf(fmaxf(px, 0.f), 127.f);
      float pyc = fminf(fmaxf(py, 0.f), 127.f);
      float glt = (1.f + ((float)r0 - pxc)) * (1.f + ((float)c0 - pyc));
      float grb = (1.f - ((float)r1 - pxc)) * (1.f - ((float)c1 - pyc));
      float glb = (1.f + ((float)r0 - pxc)) * (1.f - ((float)c1 - pyc));
      float grt = (1.f - ((float)r1 - pxc)) * (1.f + ((float)c0 - pyc));
      int base = ((bb * 128 + ii) * NP + n) * 128 + j;
      midx[base] = r0 | (r1 << 8) | (c0 << 16) | (c1 << 24);
      mw[base] = make_float4(glt, grb, glb, grt);
    }
  }
}

// ---------------------------------------------------------------------------
// Fused gather + GEMM. One block per (b,ii): Mtile=128 (j), Ntile=256 (o).
// 512 threads = 8 waves; wave (mh, oq) owns 64m x 64o. BK=32, double-buffered
// LDS, one barrier per chunk. Gather uses 2 float2 loads per channel.
// ---------------------------------------------------------------------------
__global__ __launch_bounds__(512, 4) void k_gemm(
    const float* __restrict__ x, const bf16_t* __restrict__ bt,
    const int* __restrict__ midx, const float4* __restrict__ mw,
    float* __restrict__ out)
{
  // A0 @0 (10240) | A1 @10240 | B0 @20480 (16384) | B1 @36864 | mi @53248 | mwl @57856
  __shared__ __align__(16) char smem[76288];
  int*    mi  = (int*)   (smem + 53248);
  float4* mwl = (float4*)(smem + 57856);

  int blk = swz(blockIdx.x);
  int bb = blk >> 7, ii = blk & 127;
  int tid = threadIdx.x;
  int wave = tid >> 6, lane = tid & 63;
  int l15 = lane & 15, quad = lane >> 4;
  int mh = wave & 1;
  int oq = wave >> 1;
  int jloc = mh * 64 + lane;
  int cgrp = oq;

  {
    int base = (bb * 128 + ii) * (NP * 128);
    for (int t = tid; t < NP * 128; t += 512) mi[t] = midx[base + t];
    for (int t = tid; t < NP * 128; t += 512) mwl[t] = mw[base + t];
  }
  __syncthreads();

  const float* xb = x + (size_t)bb * CIN * HWSZ;

  f32x4 acc[4][4];
#pragma unroll
  for (int mt = 0; mt < 4; ++mt)
#pragma unroll
    for (int ot = 0; ot < 4; ++ot) acc[mt][ot] = (f32x4){0.f, 0.f, 0.f, 0.f};

#pragma unroll 1
  for (int kk = 0; kk < 36; ++kk) {
    int n = kk >> 2;
    int c0 = (kk & 3) * 32;
    bf16_t* Ald = (bf16_t*)(smem + (kk & 1) * 10240);
    bf16_t* Bld = (bf16_t*)(smem + 20480 + (kk & 1) * 16384);

    int idx = mi[n * 128 + jloc];
    float4 g = mwl[n * 128 + jloc];
    int r0 = idx & 255, r1 = (idx >> 8) & 255;
    int q0 = (idx >> 16) & 255, q1 = (idx >> 24) & 255;
    int qb = (q0 < 126) ? q0 : 126;
    bool s0 = (q0 != qb), s1 = (q1 != qb);
    int oA = r0 * 128 + qb, oB = r1 * 128 + qb;

    // ---- A gather: 8 channels, 2 x float2 per channel -> one ds_write_b128
    bf16x8 av;
#pragma unroll
    for (int it = 0; it < 8; ++it) {
      const float* p = xb + (c0 + cgrp * 8 + it) * HWSZ;
      F2 pa = *(const F2*)(p + oA);   // row r0: cols qb, qb+1
      F2 pb = *(const F2*)(p + oB);   // row r1
      float v00 = s0 ? pa.y : pa.x;   // (r0,q0) w glt
      float v01 = s1 ? pa.y : pa.x;   // (r0,q1) w glb
      float v10 = s0 ? pb.y : pb.x;   // (r1,q0) w grt
      float v11 = s1 ? pb.y : pb.x;   // (r1,q1) w grb
      av[it] = (bf16_t)(g.x * v00 + g.y * v11 + g.z * v01 + g.w * v10);
    }
    *(bf16x8*)(Ald + jloc * 40 + cgrp * 8) = av;

    // ---- B stage: 256 o x 64 B for this k-chunk
#pragma unroll
    for (int s = 0; s < 2; ++s) {
      int id = tid + s * 512;
      int o = id >> 2, gg = id & 3;
      *(uint4*)((char*)Bld + o * 64 + gg * 16) =
          *(const uint4*)((const char*)bt + (size_t)o * (KDIM * 2) + kk * 64 + gg * 16);
    }
    __syncthreads();

    // ---- fragments + MFMA
    bf16x8 af[4], bfr[4];
#pragma unroll
    for (int mt = 0; mt < 4; ++mt)
      af[mt] = *(bf16x8*)(Ald + (mh * 64 + mt * 16 + l15) * 40 + quad * 8);
#pragma unroll
    for (int ot = 0; ot < 4; ++ot)
      bfr[ot] = *(bf16x8*)(Bld + (oq * 64 + ot * 16 + l15) * 32 + quad * 8);
#pragma unroll
    for (int mt = 0; mt < 4; ++mt)
#pragma unroll
      for (int ot = 0; ot < 4; ++ot)
        acc[mt][ot] = __builtin_amdgcn_mfma_f32_16x16x32_bf16(
            af[mt], bfr[ot], acc[mt][ot], 0, 0, 0);
  }

  // ---- epilogue: transpose 32-o x 128-j pieces through LDS, coalesced stores
  float* piece = (float*)smem;   // 32 x 132 floats
  for (int p = 0; p < 8; ++p) {
    __syncthreads();
    if (oq == (p >> 1)) {
      int otbase = (p & 1) * 2;
#pragma unroll
      for (int t2 = 0; t2 < 2; ++t2) {
        int ot = otbase + t2;
        int o_ip = t2 * 16 + l15;
#pragma unroll
        for (int mt = 0; mt < 4; ++mt) {
          int jj = mh * 64 + mt * 16 + quad * 4;
          *(f32x4*)(piece + o_ip * 132 + jj) = acc[mt][ot];
        }
      }
    }
    __syncthreads();
#pragma unroll
    for (int s = 0; s < 2; ++s) {
      int id = tid + s * 512;
      int o_ip = id >> 5, part = id & 31;
      f32x4 v = *(f32x4*)(piece + o_ip * 132 + part * 4);
      *(f32x4*)(out + (((size_t)bb * OCH + p * 32 + o_ip) * 128 + ii) * 128 + part * 4) = v;
    }
  }
}

// ---------------------------------------------------------------------------
extern "C" void kernel_launch(void* const* d_in, const int* in_sizes, int n_in,
                              void* d_out, int out_size, void* d_ws, size_t ws_size,
                              hipStream_t stream) {
  const float* x  = (const float*)d_in[0];
  const float* wp = (const float*)d_in[1];
  const float* bp = (const float*)d_in[2];
  const float* wc = (const float*)d_in[3];
  float* out = (float*)d_out;

  bf16_t* BT   = (bf16_t*)d_ws;                              // 589,824 B
  int*    MIDX = (int*)   ((char*)d_ws + (1u << 20));        // 2,359,296 B
  float4* MW   = (float4*)((char*)d_ws + (4u << 20));        // 9,437,184 B

  k_bt<<<dim3(9, 256), 128, 0, stream>>>(wc, BT);
  k_conv_meta<<<512, 256, 0, stream>>>(x, wp, bp, MIDX, MW);
  k_gemm<<<512, 512, 0, stream>>>(x, BT, MIDX, MW, out);
}